// Round 2
// baseline (16164.854 us; speedup 1.0000x reference)
//
#include <hip/hip_runtime.h>

// Tanh RNN: B=64, S=2048, I=H=512, fp32 in/out.
// prep:    w_ih,w_hh -> fp16; bias = b_ih+b_hh.
// xproj:   xp[s*64+b][h] = inputs[b][s][:] . w_ih[h][:] + bias[h]  (f16 MFMA)
// slotinit: pack state -> slot0 (fp16 qwords), poison slots 1..3.
// rnn:     16 persistent WGs (4 row-groups x 4 col-slices), w_hh in VGPRs.
//          h exchanged via relaxed agent-scope 64-bit atomics; readiness is
//          detected by polling data != POISON (fp16 NaN pattern). No fences,
//          no flags, no barriers. 4 rotating slots; consumed slots are
//          re-poisoned one step later (ordering via per-step vmcnt(0)).

typedef _Float16 half8 __attribute__((ext_vector_type(8)));
typedef float f32x4 __attribute__((ext_vector_type(4)));
typedef unsigned long long u64;

#define S_SZ 2048
#define OUT1_OFF 67108864ull   // S*B*H floats

// workspace offsets (bytes)
#define XP_OFF    0ull              // 2048*64*512*4 = 268435456
#define WIH_OFF   268435456ull      // 524288 (dead after xproj; slots reuse it)
#define WHH_OFF   268959744ull      // 524288
#define BIAS_OFF  269484032ull      // 2048
#define SLOT_OFF  WIH_OFF           // 4 slots * 8192 qwords * 8B = 262144

#define POISON 0x7FFF7FFF7FFF7FFFull

__device__ __forceinline__ float fast_tanh(float x) {
    // tanh(x) = (e^{2x}-1)/(e^{2x}+1); 2*log2(e) = 2.88539008...
    float a = exp2f(fminf(fmaxf(x * 2.8853900817779268f, -30.f), 30.f));
    return (a - 1.0f) * __builtin_amdgcn_rcpf(a + 1.0f);
}

__global__ void prep_kernel(const float* __restrict__ wih, const float* __restrict__ whh,
                            const float* __restrict__ bih, const float* __restrict__ bhh,
                            _Float16* __restrict__ wih16, _Float16* __restrict__ whh16,
                            float* __restrict__ bias)
{
    const int i = blockIdx.x * 256 + threadIdx.x;   // 1024 blocks -> 262144
    wih16[i] = (_Float16)wih[i];
    whh16[i] = (_Float16)whh[i];
    if (i < 512) bias[i] = bih[i] + bhh[i];
}

// runs AFTER xproj (slots overlap the then-dead wih16 region)
__global__ void slotinit_kernel(const float* __restrict__ state, u64* __restrict__ slotq)
{
    const int gid = blockIdx.x * 256 + threadIdx.x;  // 128 blocks -> 32768
    if (gid < 8192) {
        union { _Float16 h[4]; u64 u; } p;
        #pragma unroll
        for (int j = 0; j < 4; ++j) p.h[j] = (_Float16)state[gid * 4 + j];
        slotq[gid] = p.u;          // slot0 = h_0, row-major [64][128] qwords
    } else {
        slotq[gid] = POISON;       // slots 1..3
    }
}

// ---------------- input projection GEMM (unchanged from round 1) ----------------
typedef _Float16 half4 __attribute__((ext_vector_type(4)));

__global__ __launch_bounds__(512, 1) void xproj_kernel(
    const float* __restrict__ inputs, const _Float16* __restrict__ wih16,
    const float* __restrict__ bias, float* __restrict__ xp)
{
    __shared__ _Float16 Alds[64 * 512];
    const int s = blockIdx.x;

    for (int idx = threadIdx.x; idx < 64 * 128; idx += 512) {
        const int row = idx >> 7, chunk = idx & 127;
        const float4 v = *reinterpret_cast<const float4*>(
            inputs + ((size_t)row * S_SZ + s) * 512 + chunk * 4);
        half4 hv;
        hv[0] = (_Float16)v.x; hv[1] = (_Float16)v.y;
        hv[2] = (_Float16)v.z; hv[3] = (_Float16)v.w;
        const int bc = (chunk * 8) ^ ((row & 7) << 4);
        *reinterpret_cast<half4*>(reinterpret_cast<char*>(Alds) + row * 1024 + bc) = hv;
    }
    __syncthreads();

    const int lane = threadIdx.x & 63, w = threadIdx.x >> 6;
    const int l15 = lane & 15, lg = lane >> 4;

    f32x4 acc[4][4];
    #pragma unroll
    for (int m = 0; m < 4; ++m)
        #pragma unroll
        for (int n = 0; n < 4; ++n)
            acc[m][n] = 0.0f;

    for (int kk = 0; kk < 16; ++kk) {
        half8 af[4], bf[4];
        #pragma unroll
        for (int m = 0; m < 4; ++m) {
            const int row = m * 16 + l15;
            const int bc = (kk * 64 + lg * 16) ^ ((row & 7) << 4);
            af[m] = *reinterpret_cast<const half8*>(
                reinterpret_cast<const char*>(Alds) + row * 1024 + bc);
        }
        #pragma unroll
        for (int n = 0; n < 4; ++n) {
            const int col = w * 64 + n * 16 + l15;
            bf[n] = *reinterpret_cast<const half8*>(wih16 + (size_t)col * 512 + kk * 32 + lg * 8);
        }
        #pragma unroll
        for (int m = 0; m < 4; ++m)
            #pragma unroll
            for (int n = 0; n < 4; ++n)
                acc[m][n] = __builtin_amdgcn_mfma_f32_16x16x32_f16(af[m], bf[n], acc[m][n], 0, 0, 0);
    }

    #pragma unroll
    for (int m = 0; m < 4; ++m) {
        #pragma unroll
        for (int n = 0; n < 4; ++n) {
            const int gcol = w * 64 + n * 16 + l15;
            const float bv = bias[gcol];
            #pragma unroll
            for (int q = 0; q < 4; ++q) {
                const int grow = m * 16 + lg * 4 + q;
                xp[((size_t)s * 64 + grow) * 512 + gcol] = acc[m][n][q] + bv;
            }
        }
    }
}

// ---------------- persistent recurrence: fence-free, flag-free ----------------
// WG (r,c): batch rows r*16..+16, output cols c*128..+128. 4 waves, wave w owns
// 32 cols. Swapped MFMA: acc = mfma(w_frag, h_frag) -> lane l15 = batch row,
// reg quad = 4 consecutive output cols -> direct row-major qword packing.
__global__ __launch_bounds__(256, 1) void rnn_step_kernel(
    const _Float16* __restrict__ whh16, const float* __restrict__ xp,
    u64* __restrict__ slotq, float* __restrict__ out)
{
    const int r = blockIdx.x >> 2, c = blockIdx.x & 3;
    const int tid = threadIdx.x;
    const int lane = tid & 63, w = tid >> 6;
    const int l15 = lane & 15, lg = lane >> 4;
    const int colbase = c * 128 + w * 32;
    const int row = r * 16 + l15;                 // this thread's batch row

    // w_hh fragments (used as MFMA A operand): wf[n][kk] covers
    // j = colbase + n*16 + l15, k = kk*32 + lg*8 .. +8
    half8 wf[2][16];
    #pragma unroll
    for (int n = 0; n < 2; ++n) {
        const _Float16* wp = whh16 + (size_t)(colbase + n * 16 + l15) * 512 + lg * 8;
        #pragma unroll
        for (int kk = 0; kk < 16; ++kk)
            wf[n][kk] = *reinterpret_cast<const half8*>(wp + kk * 32);
    }

    const int qin_off  = r * 2048 + l15 * 128 + lg * 2;              // + s*8192 + kk*8 (+0/1)
    const int qout_off = r * 2048 + l15 * 128 + (colbase >> 2) + lg; // + s*8192 (+n*4)
    const int qp_off   = r * 2048 + (tid >> 4) * 128 + c * 32 + (tid & 15) * 2;

    // xp prefetch for t=0
    f32x4 xpv[2];
    {
        const float* xprow = xp + (size_t)row * 512 + colbase + lg * 4;
        xpv[0] = *reinterpret_cast<const f32x4*>(xprow);
        xpv[1] = *reinterpret_cast<const f32x4*>(xprow + 16);
    }

    long budget = 30000000L;  // global retry budget (anti-hang; never hit if correct)

    #pragma unroll 1
    for (int t = 0; t < S_SZ; ++t) {
        // ---- poll-read h_t from slot t&3 (32 qwords -> A... B fragments) ----
        u64* qin = slotq + (size_t)((t & 3) * 8192 + qin_off);
        u64 q[32];
        for (;;) {
            #pragma unroll
            for (int kk = 0; kk < 16; ++kk) {
                q[2 * kk]     = __hip_atomic_load(qin + kk * 8,     __ATOMIC_RELAXED, __HIP_MEMORY_SCOPE_AGENT);
                q[2 * kk + 1] = __hip_atomic_load(qin + kk * 8 + 1, __ATOMIC_RELAXED, __HIP_MEMORY_SCOPE_AGENT);
            }
            bool ok = true;
            #pragma unroll
            for (int i = 0; i < 32; ++i) ok &= (q[i] != POISON);
            if (ok || --budget <= 0) break;
        }

        // ---- MFMA: acc[n] = w_slice . h^T ----
        f32x4 acc0 = 0.0f, acc1 = 0.0f;
        #pragma unroll
        for (int kk = 0; kk < 16; ++kk) {
            union { u64 u[2]; half8 h; } cvt;
            cvt.u[0] = q[2 * kk]; cvt.u[1] = q[2 * kk + 1];
            acc0 = __builtin_amdgcn_mfma_f32_16x16x32_f16(wf[0][kk], cvt.h, acc0, 0, 0, 0);
            acc1 = __builtin_amdgcn_mfma_f32_16x16x32_f16(wf[1][kk], cvt.h, acc1, 0, 0, 0);
        }

        // ---- tanh + pack ----
        f32x4 f0, f1;
        union { _Float16 h[4]; u64 u; } p0, p1;
        #pragma unroll
        for (int qq = 0; qq < 4; ++qq) {
            f0[qq] = fast_tanh(acc0[qq] + xpv[0][qq]);
            f1[qq] = fast_tanh(acc1[qq] + xpv[1][qq]);
            p0.h[qq] = (_Float16)f0[qq];
            p1.h[qq] = (_Float16)f1[qq];
        }

        asm volatile("" ::: "memory");
        // drain: previous step's poison + out stores (issued ~1 step ago -> cheap).
        // Guarantees poison@t-1 is globally visible before h_{t+1} becomes visible.
        asm volatile("s_waitcnt vmcnt(0)" ::: "memory");

        // ---- publish h_{t+1} to slot (t+1)&3 ----
        u64* qout = slotq + (size_t)(((t + 1) & 3) * 8192 + qout_off);
        __hip_atomic_store(qout,     p0.u, __ATOMIC_RELAXED, __HIP_MEMORY_SCOPE_AGENT);
        __hip_atomic_store(qout + 4, p1.u, __ATOMIC_RELAXED, __HIP_MEMORY_SCOPE_AGENT);

        // ---- re-poison slot (t-1)&3 (safe: everyone's stores@t certify reads@t) ----
        if (t > 0) {
            u64* qp = slotq + (size_t)(((t - 1) & 3) * 8192 + qp_off);
            __hip_atomic_store(qp,     POISON, __ATOMIC_RELAXED, __HIP_MEMORY_SCOPE_AGENT);
            __hip_atomic_store(qp + 1, POISON, __ATOMIC_RELAXED, __HIP_MEMORY_SCOPE_AGENT);
        }

        // ---- fp32 outputs (fire-and-forget, off critical path) ----
        float* orow = out + ((size_t)t * 64 + row) * 512 + colbase + lg * 4;
        __builtin_nontemporal_store(f0, reinterpret_cast<f32x4*>(orow));
        __builtin_nontemporal_store(f1, reinterpret_cast<f32x4*>(orow + 16));

        if (t == S_SZ - 1) {
            #pragma unroll
            for (int qq = 0; qq < 4; ++qq) {
                out[OUT1_OFF + (size_t)(colbase + lg * 4 + qq) * 64 + row] = f0[qq];
                out[OUT1_OFF + (size_t)(colbase + 16 + lg * 4 + qq) * 64 + row] = f1[qq];
            }
        }

        // ---- prefetch xp for t+1 ----
        if (t + 1 < S_SZ) {
            const float* xprow = xp + ((size_t)(t + 1) * 64 + row) * 512 + colbase + lg * 4;
            xpv[0] = *reinterpret_cast<const f32x4*>(xprow);
            xpv[1] = *reinterpret_cast<const f32x4*>(xprow + 16);
        }
    }
}

extern "C" void kernel_launch(void* const* d_in, const int* in_sizes, int n_in,
                              void* d_out, int out_size, void* d_ws, size_t ws_size,
                              hipStream_t stream)
{
    const float* inputs = (const float*)d_in[0];
    const float* state  = (const float*)d_in[1];
    const float* w_ih   = (const float*)d_in[2];
    const float* b_ih   = (const float*)d_in[3];
    const float* w_hh   = (const float*)d_in[4];
    const float* b_hh   = (const float*)d_in[5];
    float* out = (float*)d_out;
    char* ws = (char*)d_ws;

    float*    xp    = (float*)(ws + XP_OFF);
    _Float16* wih16 = (_Float16*)(ws + WIH_OFF);
    _Float16* whh16 = (_Float16*)(ws + WHH_OFF);
    float*    bias  = (float*)(ws + BIAS_OFF);
    u64*      slotq = (u64*)(ws + SLOT_OFF);   // overlaps wih16 (dead after xproj)

    prep_kernel<<<1024, 256, 0, stream>>>(w_ih, w_hh, b_ih, b_hh, wih16, whh16, bias);
    xproj_kernel<<<S_SZ, 512, 0, stream>>>(inputs, wih16, bias, xp);
    slotinit_kernel<<<128, 256, 0, stream>>>(state, slotq);
    rnn_step_kernel<<<16, 256, 0, stream>>>(whh16, xp, slotq, out);
}